// Round 5
// baseline (142.044 us; speedup 1.0000x reference)
//
#include <hip/hip_runtime.h>

// MultiboxLoss anchor matching: B=64, T=100, A=8732, NUM_CLASSES=21
// out = [loc (B,A,4) f32][conf (B,A) as f32]
// Round 5: (a) 4 anchors/thread, 128-thr blocks — amortizes the per-target
// wave reduction (measured ~half the issue budget at 2 anchors/thread) over
// 2x the anchors; (b) phaseA writes out directly, k_encode replaced by a
// 64-block k_fixup for the <=100 overridden anchors per batch.
//   ws: [0, 51200): u64 keys[B*T] — (iou_bits<<32)|~anchor, atomicMax
#define BB 64
#define TT 100
#define AA 8732
#define CHUNK 512                         // anchors per phase-A block (128 thr x 4)
#define NCHUNK ((AA + CHUNK - 1) / CHUNK) // 18

typedef unsigned long long u64;
typedef unsigned int u32;

// Bit-exact (vs numpy f32) IoU: _rn intrinsics block fp-contract fusion.
__device__ __forceinline__ float iou_f(float bx1, float by1, float bx2, float by2, float areab,
                                       float ax1, float ay1, float ax2, float ay2, float areaa) {
    float dx = fmaxf(__fsub_rn(fminf(bx2, ax2), fmaxf(bx1, ax1)), 0.0f);
    float dy = fmaxf(__fsub_rn(fminf(by2, ay2), fmaxf(by1, ay1)), 0.0f);
    float inter = __fmul_rn(dx, dy);
    float uni = __fsub_rn(__fadd_rn(areab, areaa), inter);
    return inter / uni;  // IEEE div, matches numpy
}

// 4 interleaved wave64 max reductions via DPP; lane 63 holds each wave max.
__device__ __forceinline__ void wave_max63_x4(float& x0, float& x1, float& x2, float& x3) {
#define DPP4(ctrl)                                                                              \
    {                                                                                           \
        int t0 = __builtin_amdgcn_update_dpp(__float_as_int(x0), __float_as_int(x0), (ctrl), 0xf, 0xf, false); \
        int t1 = __builtin_amdgcn_update_dpp(__float_as_int(x1), __float_as_int(x1), (ctrl), 0xf, 0xf, false); \
        int t2 = __builtin_amdgcn_update_dpp(__float_as_int(x2), __float_as_int(x2), (ctrl), 0xf, 0xf, false); \
        int t3 = __builtin_amdgcn_update_dpp(__float_as_int(x3), __float_as_int(x3), (ctrl), 0xf, 0xf, false); \
        x0 = fmaxf(x0, __int_as_float(t0));                                                     \
        x1 = fmaxf(x1, __int_as_float(t1));                                                     \
        x2 = fmaxf(x2, __int_as_float(t2));                                                     \
        x3 = fmaxf(x3, __int_as_float(t3));                                                     \
    }
    DPP4(0x111)  // row_shr:1
    DPP4(0x112)  // row_shr:2
    DPP4(0x114)  // row_shr:4
    DPP4(0x118)  // row_shr:8   -> lane15 of each row16 = row max
    DPP4(0x142)  // row_bcast:15
    DPP4(0x143)  // row_bcast:31 -> lane63 = wave max
#undef DPP4
}

__global__ __launch_bounds__(256) void k_init(u64* __restrict__ keys) {
    int i = blockIdx.x * 256 + threadIdx.x;
    if (i < BB * TT) keys[i] = 0ULL;
}

// block = (b, 512-anchor chunk); 128 threads; anchor a = c0 + k*128 + tid,
// k=0..3 (strided => coalesced loads/stores; k*128 dominates lane in index,
// so per-target tie-break = k-priority then smallest lane = smallest anchor).
__global__ __launch_bounds__(128) void k_phaseA(const float* __restrict__ targets,
                                                const float* __restrict__ anchors,
                                                u64* __restrict__ keys,
                                                float* __restrict__ out) {
    const int b = blockIdx.y;
    const int c0 = blockIdx.x * CHUNK;
    const int tid = threadIdx.x;
    const int lane = tid & 63, wv = tid >> 6;

    __shared__ float4 sh_box[TT];
    __shared__ float sh_lab[TT];
    __shared__ u64 sh_red[TT][2];

    if (tid < TT) {
        const float* tg = targets + ((size_t)b * TT + tid) * 5;
        sh_box[tid] = make_float4(tg[0], tg[1], tg[2], tg[3]);
        sh_lab[tid] = tg[4];
    }
    __syncthreads();

    // Anchor center + point-form. OOB dummy (0,0,0,0,area=1): box coords >= 0
    // => intersection exactly 0 => IoU exactly 0; never beats a real anchor
    // (ties resolve to the smaller real index via ~a in the key).
    float acx[4], acy[4], aw[4], ah[4];
    float ax1[4], ay1[4], ax2[4], ay2[4], aar[4];
    #pragma unroll
    for (int k = 0; k < 4; ++k) {
        int a = c0 + k * 128 + tid;
        if (a < AA) {
            float4 c = *(const float4*)(anchors + (size_t)a * 4);
            acx[k] = c.x; acy[k] = c.y; aw[k] = c.z; ah[k] = c.w;
            float hx = __fmul_rn(c.z, 0.5f), hy = __fmul_rn(c.w, 0.5f);
            ax1[k] = __fsub_rn(c.x, hx); ay1[k] = __fsub_rn(c.y, hy);
            ax2[k] = __fadd_rn(c.x, hx); ay2[k] = __fadd_rn(c.y, hy);
            aar[k] = __fmul_rn(__fsub_rn(ax2[k], ax1[k]), __fsub_rn(ay2[k], ay1[k]));
        } else {
            acx[k] = acy[k] = aw[k] = ah[k] = 1.f;  // unused (store guarded)
            ax1[k] = ay1[k] = ax2[k] = ay2[k] = 0.f;
            aar[k] = 1.f;
        }
    }

    float best[4] = {-1.f, -1.f, -1.f, -1.f};
    int gi[4] = {0, 0, 0, 0};

    for (int t = 0; t < TT; t += 4) {
        float4 B[4];
        float ar[4];
        #pragma unroll
        for (int j = 0; j < 4; ++j) {
            B[j] = sh_box[t + j];
            ar[j] = __fmul_rn(__fsub_rn(B[j].z, B[j].x), __fsub_rn(B[j].w, B[j].y));
        }
        float v[4][4];  // [target j][anchor k] — 16 independent IEEE divs
        #pragma unroll
        for (int j = 0; j < 4; ++j) {
            #pragma unroll
            for (int k = 0; k < 4; ++k)
                v[j][k] = iou_f(B[j].x, B[j].y, B[j].z, B[j].w, ar[j],
                                ax1[k], ay1[k], ax2[k], ay2[k], aar[k]);
        }
        // per-anchor argmax over t: ascending t, strict > => first-t-wins
        #pragma unroll
        for (int j = 0; j < 4; ++j) {
            #pragma unroll
            for (int k = 0; k < 4; ++k)
                if (v[j][k] > best[k]) { best[k] = v[j][k]; gi[k] = t + j; }
        }
        // per-target argmax over this wave's 256 anchors
        float vm[4];
        #pragma unroll
        for (int j = 0; j < 4; ++j)
            vm[j] = fmaxf(fmaxf(v[j][0], v[j][1]), fmaxf(v[j][2], v[j][3]));
        float w0 = vm[0], w1 = vm[1], w2 = vm[2], w3 = vm[3];
        wave_max63_x4(w0, w1, w2, w3);
        u32 wmb[4];
        wmb[0] = (u32)__builtin_amdgcn_readlane(__float_as_int(w0), 63);
        wmb[1] = (u32)__builtin_amdgcn_readlane(__float_as_int(w1), 63);
        wmb[2] = (u32)__builtin_amdgcn_readlane(__float_as_int(w2), 63);
        wmb[3] = (u32)__builtin_amdgcn_readlane(__float_as_int(w3), 63);
        #pragma unroll
        for (int j = 0; j < 4; ++j) {
            float wmf = __uint_as_float(wmb[j]);
            u64 e0 = __ballot(v[j][0] == wmf);   // winners per k (lane order =
            u64 e1 = __ballot(v[j][1] == wmf);   // anchor order within k)
            u64 e2 = __ballot(v[j][2] == wmf);
            u64 e3 = __ballot(v[j][3] == wmf);
            u32 ksel, wl;                        // smallest k first, then
            if (e0)      { ksel = 0; wl = (u32)(__ffsll((long long)e0) - 1); }
            else if (e1) { ksel = 1; wl = (u32)(__ffsll((long long)e1) - 1); }
            else if (e2) { ksel = 2; wl = (u32)(__ffsll((long long)e2) - 1); }
            else         { ksel = 3; wl = (u32)(__ffsll((long long)e3) - 1); }
            u32 g = (u32)c0 + ksel * 128u + (u32)(wv * 64) + wl;  // smallest anchor
            u64 key = (((u64)wmb[j]) << 32) | (u64)(u32)~g;
            if (lane == 0) sh_red[t + j][wv] = key;
        }
    }
    __syncthreads();

    if (tid < TT) {
        u64 m0 = sh_red[tid][0], m1 = sh_red[tid][1];
        atomicMax(&keys[b * TT + tid], m0 > m1 ? m0 : m1);
    }

    // Epilogue: write loc/conf for the no-override case (k_fixup patches the
    // <=100 overridden anchors per batch afterwards). Coalesced per k.
    #pragma unroll
    for (int k = 0; k < 4; ++k) {
        int a = c0 + k * 128 + tid;
        if (a >= AA) continue;
        int g = gi[k];
        float4 m = sh_box[g];
        float cx = (m.x + m.z) * 0.5f, cy = (m.y + m.w) * 0.5f;
        float w = m.z - m.x, h = m.w - m.y;
        float l0 = (cx - acx[k]) / (0.1f * aw[k]);
        float l1 = (cy - acy[k]) / (0.1f * ah[k]);
        float l2 = logf(w / aw[k]) / 0.2f;
        float l3 = logf(h / ah[k]) / 0.2f;
        size_t base = ((size_t)b * AA + a) * 4;
        *(float4*)(out + base) = make_float4(l0, l1, l2, l3);
        float conf = (best[k] >= 0.5f) ? (float)(int)(sh_lab[g] + 1.0f) : 0.0f;
        out[(size_t)BB * AA * 4 + (size_t)b * AA + a] = conf;
    }
}

// Fixup: block per batch. For each t, its argmax anchor gets gi=t, ov=1.0
// (conf always label+1). Duplicate anchors: only the largest t writes
// (= last-wins, matching .at[].set semantics).
__global__ __launch_bounds__(128) void k_fixup(const float* __restrict__ targets,
                                               const float* __restrict__ anchors,
                                               const u64* __restrict__ keys,
                                               float* __restrict__ out) {
    const int b = blockIdx.x;
    const int t = threadIdx.x;
    __shared__ u32 sh_a[TT];
    if (t < TT) sh_a[t] = ~(u32)(keys[(size_t)b * TT + t] & 0xFFFFFFFFull);
    __syncthreads();
    if (t >= TT) return;
    u32 a = sh_a[t];
    bool last = true;
    for (int t2 = t + 1; t2 < TT; ++t2)
        if (sh_a[t2] == a) last = false;
    if (!last) return;
    const float* tg = targets + ((size_t)b * TT + t) * 5;
    float4 anc = *(const float4*)(anchors + (size_t)a * 4);
    float mx1 = tg[0], my1 = tg[1], mx2 = tg[2], my2 = tg[3];
    float cx = (mx1 + mx2) * 0.5f, cy = (my1 + my2) * 0.5f;
    float w = mx2 - mx1, h = my2 - my1;
    float l0 = (cx - anc.x) / (0.1f * anc.z);
    float l1 = (cy - anc.y) / (0.1f * anc.w);
    float l2 = logf(w / anc.z) / 0.2f;
    float l3 = logf(h / anc.w) / 0.2f;
    size_t base = ((size_t)b * AA + a) * 4;
    *(float4*)(out + base) = make_float4(l0, l1, l2, l3);
    out[(size_t)BB * AA * 4 + (size_t)b * AA + a] = (float)(int)(tg[4] + 1.0f);
}

extern "C" void kernel_launch(void* const* d_in, const int* in_sizes, int n_in,
                              void* d_out, int out_size, void* d_ws, size_t ws_size,
                              hipStream_t stream) {
    const float* targets = (const float*)d_in[0];  // (B,T,5)
    const float* anchors = (const float*)d_in[1];  // (A,4)
    float* out = (float*)d_out;
    u64* keys = (u64*)d_ws;                        // 51.2 KB

    k_init<<<(BB * TT + 255) / 256, 256, 0, stream>>>(keys);
    dim3 gA(NCHUNK, BB);
    k_phaseA<<<gA, 128, 0, stream>>>(targets, anchors, keys, out);
    k_fixup<<<BB, 128, 0, stream>>>(targets, anchors, keys, out);
}